// Round 1
// 826.456 us; speedup vs baseline: 2.5609x; 2.5609x over previous
//
#include <hip/hip_runtime.h>
#include <math.h>

#define TOK_I 4096   // I
#define NE 8         // experts
#define NR 16        // lora rank
#define NQ 4096      // q out dim
#define NV 1024      // v out dim
#define LORA_SCALE 2.0f

#define BM2 32       // tokens per block, low-rank kernel
#define KB2 128      // K-chunk, low-rank kernel
#define BM3 32       // tokens per block, expand kernel

// ---------------------------------------------------------------------------
// Fallback: previous fused kernel (used only if workspace is too small).
// ---------------------------------------------------------------------------
__global__ __launch_bounds__(256) void qvlora_fused_kernel(
    const float* __restrict__ h, const float* __restrict__ rw,
    const float* __restrict__ qa, const float* __restrict__ qb,
    const float* __restrict__ va, const float* __restrict__ vb,
    float* __restrict__ qout, float* __restrict__ vout)
{
    const int tok  = blockIdx.x;
    const int tid  = threadIdx.x;
    const int lane = tid & 63;
    const int wave = tid >> 6;

    __shared__ float red8[4][8];
    __shared__ float red32[4][32];
    __shared__ float sLow[32];
    __shared__ float sGate;
    __shared__ int   sSel;

    const float4* h4 = (const float4*)(h + (long)tok * TOK_I);
    float4 hreg[4];
#pragma unroll
    for (int k = 0; k < 4; ++k) hreg[k] = h4[tid + 256 * k];

    float lacc[NE];
#pragma unroll
    for (int e = 0; e < NE; ++e) lacc[e] = 0.f;
    const float4* rw4 = (const float4*)rw;
#pragma unroll
    for (int k = 0; k < 4; ++k) {
        float4 hv = hreg[k];
        int f = tid + 256 * k;
#pragma unroll
        for (int e = 0; e < NE; ++e) {
            float4 wv = rw4[e * 1024 + f];
            lacc[e] += hv.x * wv.x + hv.y * wv.y + hv.z * wv.z + hv.w * wv.w;
        }
    }
#pragma unroll
    for (int off = 32; off >= 1; off >>= 1)
#pragma unroll
        for (int e = 0; e < NE; ++e) lacc[e] += __shfl_down(lacc[e], off);
    if (lane == 0)
#pragma unroll
        for (int e = 0; e < NE; ++e) red8[wave][e] = lacc[e];
    __syncthreads();

    if (tid == 0) {
        float lg[NE];
#pragma unroll
        for (int e = 0; e < NE; ++e)
            lg[e] = red8[0][e] + red8[1][e] + red8[2][e] + red8[3][e];
        int best = 0; float mx = lg[0];
#pragma unroll
        for (int e = 1; e < NE; ++e) if (lg[e] > mx) { mx = lg[e]; best = e; }
        float s = 0.f;
#pragma unroll
        for (int e = 0; e < NE; ++e) s += __expf(lg[e] - mx);
        sSel = best; sGate = LORA_SCALE / s;
    }
    __syncthreads();

    const int e = sSel;
    float acc[32];
#pragma unroll
    for (int c = 0; c < 32; ++c) acc[c] = 0.f;
    const float4* qa4 = (const float4*)(qa + (long)e * TOK_I * NR);
    const float4* va4 = (const float4*)(va + (long)e * TOK_I * NR);
#pragma unroll
    for (int k = 0; k < 4; ++k) {
        float4 hv = hreg[k];
        float he[4] = {hv.x, hv.y, hv.z, hv.w};
        int i0 = 4 * (tid + 256 * k);
#pragma unroll
        for (int d = 0; d < 4; ++d) {
            int row4 = (i0 + d) * 4;
#pragma unroll
            for (int r4 = 0; r4 < 4; ++r4) {
                float4 wq = qa4[row4 + r4];
                float4 wv = va4[row4 + r4];
                acc[4*r4+0] += he[d]*wq.x; acc[4*r4+1] += he[d]*wq.y;
                acc[4*r4+2] += he[d]*wq.z; acc[4*r4+3] += he[d]*wq.w;
                acc[16+4*r4+0] += he[d]*wv.x; acc[16+4*r4+1] += he[d]*wv.y;
                acc[16+4*r4+2] += he[d]*wv.z; acc[16+4*r4+3] += he[d]*wv.w;
            }
        }
    }
#pragma unroll
    for (int off = 32; off >= 1; off >>= 1)
#pragma unroll
        for (int c = 0; c < 32; ++c) acc[c] += __shfl_down(acc[c], off);
    if (lane == 0)
#pragma unroll
        for (int c = 0; c < 32; ++c) red32[wave][c] = acc[c];
    __syncthreads();
    if (tid < 32) {
        float v = red32[0][tid] + red32[1][tid] + red32[2][tid] + red32[3][tid];
        sLow[tid] = v * sGate;
    }
    __syncthreads();

    float lq[NR], lv[NR];
#pragma unroll
    for (int r = 0; r < NR; ++r) { lq[r] = sLow[r]; lv[r] = sLow[16 + r]; }
    const float4* qb4 = (const float4*)(qb + (long)e * NR * NQ);
    const float4* vb4 = (const float4*)(vb + (long)e * NR * NV);
    float4* qo4 = (float4*)(qout + (long)tok * NQ);
    float4* vo4 = (float4*)(vout + (long)tok * NV);
    {
        float4 o = {0,0,0,0};
#pragma unroll
        for (int r = 0; r < NR; ++r) {
            float4 w = vb4[r * 256 + tid];
            o.x += lv[r]*w.x; o.y += lv[r]*w.y; o.z += lv[r]*w.z; o.w += lv[r]*w.w;
        }
        vo4[tid] = o;
    }
#pragma unroll
    for (int m = 0; m < 4; ++m) {
        float4 o = {0,0,0,0};
        int f = tid + 256 * m;
#pragma unroll
        for (int r = 0; r < NR; ++r) {
            float4 w = qb4[r * 1024 + f];
            o.x += lq[r]*w.x; o.y += lq[r]*w.y; o.z += lq[r]*w.z; o.w += lq[r]*w.w;
        }
        qo4[f] = o;
    }
}

// ---------------------------------------------------------------------------
// Kernel 1: router. 2 tokens per 256-thread block. Per-token logit reduction
// is bitwise-identical to the previously-passing kernel (same element->thread
// mapping, same shfl tree, same wave-sum order), so expert selection matches.
// Scatters token ids into per-expert lists (order irrelevant: each token
// writes only its own output row later).
// ---------------------------------------------------------------------------
__global__ __launch_bounds__(256) void router_kernel(
    const float* __restrict__ h, const float* __restrict__ rw,
    float* __restrict__ gate, int* __restrict__ tlist,
    int* __restrict__ count, int T)
{
    const int tok0 = blockIdx.x * 2;
    const int tid  = threadIdx.x;
    const int lane = tid & 63;
    const int wave = tid >> 6;

    __shared__ float red[2][4][NE];

    const float4* h4  = (const float4*)h;
    const float4* rw4 = (const float4*)rw;

    const int tA = tok0;
    const int tB = (tok0 + 1 < T) ? tok0 + 1 : tok0;   // dup-safe tail

    float4 hreg[2][4];
#pragma unroll
    for (int k = 0; k < 4; ++k) {
        hreg[0][k] = h4[(long)tA * 1024 + tid + 256 * k];
        hreg[1][k] = h4[(long)tB * 1024 + tid + 256 * k];
    }

    float lacc[2][NE];
#pragma unroll
    for (int j = 0; j < 2; ++j)
#pragma unroll
        for (int e = 0; e < NE; ++e) lacc[j][e] = 0.f;

#pragma unroll
    for (int k = 0; k < 4; ++k) {
        int f = tid + 256 * k;
        float4 h0 = hreg[0][k], h1 = hreg[1][k];
#pragma unroll
        for (int e = 0; e < NE; ++e) {
            float4 wv = rw4[e * 1024 + f];
            lacc[0][e] += h0.x*wv.x + h0.y*wv.y + h0.z*wv.z + h0.w*wv.w;
            lacc[1][e] += h1.x*wv.x + h1.y*wv.y + h1.z*wv.z + h1.w*wv.w;
        }
    }
#pragma unroll
    for (int off = 32; off >= 1; off >>= 1)
#pragma unroll
        for (int j = 0; j < 2; ++j)
#pragma unroll
            for (int e = 0; e < NE; ++e)
                lacc[j][e] += __shfl_down(lacc[j][e], off);

    if (lane == 0)
#pragma unroll
        for (int j = 0; j < 2; ++j)
#pragma unroll
            for (int e = 0; e < NE; ++e) red[j][wave][e] = lacc[j][e];
    __syncthreads();

    if (tid < 2) {
        int tk = tok0 + tid;
        if (tk < T) {
            float lg[NE];
#pragma unroll
            for (int e = 0; e < NE; ++e)
                lg[e] = red[tid][0][e] + red[tid][1][e] + red[tid][2][e] + red[tid][3][e];
            int best = 0; float mx = lg[0];
#pragma unroll
            for (int e = 1; e < NE; ++e) if (lg[e] > mx) { mx = lg[e]; best = e; }
            float s = 0.f;
#pragma unroll
            for (int e = 0; e < NE; ++e) s += __expf(lg[e] - mx);
            gate[tk] = LORA_SCALE / s;                 // max prob = 1/s
            int pos = atomicAdd(&count[best], 1);
            tlist[best * T + pos] = tk;
        }
    }
}

// ---------------------------------------------------------------------------
// Kernel 2: grouped low-rank projection. Block (chunk, expert) handles 32
// tokens of one expert. low[tok][0:16]=h@qa[e]*gate, [16:32]=h@va[e]*gate.
// h staged transposed in LDS (conflict-free reads), [qa|va] chunk in LDS.
// Weight panel read once per 32 tokens (16x amortization vs old kernel).
// ---------------------------------------------------------------------------
__global__ __launch_bounds__(256) void lowrank_kernel(
    const float* __restrict__ h, const float* __restrict__ qa,
    const float* __restrict__ va, const float* __restrict__ gate,
    const int* __restrict__ tlist, const int* __restrict__ count,
    float* __restrict__ low, int T)
{
    const int e   = blockIdx.y;
    const int cnt = count[e];
    const int m0  = blockIdx.x * BM2;
    if (m0 >= cnt) return;
    const int tid = threadIdx.x;

    __shared__ float h_s[KB2][BM2 + 1];   // [k][m], +1 pad spreads write banks
    __shared__ float a_s[KB2][32];        // [k][r]: r<16 qa, r>=16 va
    __shared__ int   tl_s[BM2];
    __shared__ float g_s[BM2];

    if (tid < BM2) {
        int idx = m0 + tid;
        int tk = (idx < cnt) ? tlist[e * T + idx] : -1;
        tl_s[tid] = tk;
        g_s[tid]  = (tk >= 0) ? gate[tk] : 0.f;
    }
    __syncthreads();

    const int m  = tid & 31;    // token within block
    const int rg = tid >> 5;    // 0..7 -> r = rg*4..rg*4+3
    float4 acc = {0.f, 0.f, 0.f, 0.f};

    const float4* h4  = (const float4*)h;
    const float4* qa4 = (const float4*)(qa + (long)e * TOK_I * NR);
    const float4* va4 = (const float4*)(va + (long)e * TOK_I * NR);
    float4* a_s4 = (float4*)a_s;

    const int sm  = tid >> 3;        // staging: token row 0..31
    const int skq = tid & 7;         // staging: col-quarter
    const int stl = tl_s[sm];

    for (int k0 = 0; k0 < TOK_I; k0 += KB2) {
        // stage h transposed: each thread 4 consecutive float4 along k
#pragma unroll
        for (int i = 0; i < 4; ++i) {
            int kq = skq + 8 * i;                         // float4 col 0..31
            float4 hv = (stl >= 0) ? h4[(long)stl * 1024 + (k0 >> 2) + kq]
                                   : make_float4(0.f, 0.f, 0.f, 0.f);
            int kk = kq * 4;
            h_s[kk + 0][sm] = hv.x; h_s[kk + 1][sm] = hv.y;
            h_s[kk + 2][sm] = hv.z; h_s[kk + 3][sm] = hv.w;
        }
        // stage [qa|va] chunk: linear float4 fill
#pragma unroll
        for (int i = 0; i < 4; ++i) {
            int lin  = tid * 4 + i;          // 0..1023
            int kk   = lin >> 3;             // 0..127
            int slot = lin & 7;              // 0..3 qa, 4..7 va
            float4 wv = (slot < 4) ? qa4[(long)(k0 + kk) * 4 + slot]
                                   : va4[(long)(k0 + kk) * 4 + (slot - 4)];
            a_s4[kk * 8 + slot] = wv;
        }
        __syncthreads();
#pragma unroll 8
        for (int k = 0; k < KB2; ++k) {
            float  hv = h_s[k][m];           // lanes stride-1: conflict-free
            float4 av = a_s4[k * 8 + rg];    // wave-uniform-ish: broadcast
            acc.x += hv * av.x; acc.y += hv * av.y;
            acc.z += hv * av.z; acc.w += hv * av.w;
        }
        __syncthreads();
    }

    float g = g_s[m];
    acc.x *= g; acc.y *= g; acc.z *= g; acc.w *= g;
    int tk = tl_s[m];
    if (tk >= 0) {
        float4* low4 = (float4*)low;
        low4[(long)tk * 8 + rg] = acc;
    }
}

// ---------------------------------------------------------------------------
// Kernel 3: grouped expansion. Block (chunk, expert) expands 32 tokens.
// qb/vb columns held in registers (16 float4), low broadcast from LDS,
// coalesced float4 stores. Write-bound by design.
// ---------------------------------------------------------------------------
__global__ __launch_bounds__(256) void expand_kernel(
    const float* __restrict__ low, const float* __restrict__ qb,
    const float* __restrict__ vb, const int* __restrict__ tlist,
    const int* __restrict__ count,
    float* __restrict__ qout, float* __restrict__ vout, int T)
{
    const int e   = blockIdx.y;
    const int cnt = count[e];
    const int m0  = blockIdx.x * BM3;
    if (m0 >= cnt) return;
    const int tid = threadIdx.x;

    __shared__ float lq_s[BM3][NR];
    __shared__ float lv_s[BM3][NR];
    __shared__ int   tl_s[BM3];

    if (tid < BM3) {
        int idx = m0 + tid;
        tl_s[tid] = (idx < cnt) ? tlist[e * T + idx] : -1;
    }
    __syncthreads();
    {
        int mm = tid >> 3, rg = tid & 7;
        int tk = tl_s[mm];
        const float4* low4 = (const float4*)low;
        float4 v = (tk >= 0) ? low4[(long)tk * 8 + rg]
                             : make_float4(0.f, 0.f, 0.f, 0.f);
        if (rg < 4) ((float4*)lq_s[mm])[rg]     = v;
        else        ((float4*)lv_s[mm])[rg - 4] = v;
    }
    __syncthreads();

    const float4* qb4 = (const float4*)(qb + (long)e * NR * NQ);
    const float4* vb4 = (const float4*)(vb + (long)e * NR * NV);
    float4* qo4 = (float4*)qout;
    float4* vo4 = (float4*)vout;

#pragma unroll
    for (int c = 0; c < 4; ++c) {
        int n4 = tid + 256 * c;
        float4 w[NR];
#pragma unroll
        for (int r = 0; r < NR; ++r) w[r] = qb4[r * 1024 + n4];
        for (int mm = 0; mm < BM3; ++mm) {
            int tk = tl_s[mm];
            if (tk < 0) break;               // packed: uniform across block
            float4 o = {0.f, 0.f, 0.f, 0.f};
#pragma unroll
            for (int r = 0; r < NR; ++r) {
                float l = lq_s[mm][r];       // broadcast
                o.x += l * w[r].x; o.y += l * w[r].y;
                o.z += l * w[r].z; o.w += l * w[r].w;
            }
            qo4[(long)tk * 1024 + n4] = o;
        }
    }
    {
        int n4 = tid;
        float4 w[NR];
#pragma unroll
        for (int r = 0; r < NR; ++r) w[r] = vb4[r * 256 + n4];
        for (int mm = 0; mm < BM3; ++mm) {
            int tk = tl_s[mm];
            if (tk < 0) break;
            float4 o = {0.f, 0.f, 0.f, 0.f};
#pragma unroll
            for (int r = 0; r < NR; ++r) {
                float l = lv_s[mm][r];
                o.x += l * w[r].x; o.y += l * w[r].y;
                o.z += l * w[r].z; o.w += l * w[r].w;
            }
            vo4[(long)tk * 256 + n4] = o;
        }
    }
}

// ---------------------------------------------------------------------------
extern "C" void kernel_launch(void* const* d_in, const int* in_sizes, int n_in,
                              void* d_out, int out_size, void* d_ws, size_t ws_size,
                              hipStream_t stream) {
    const float* h  = (const float*)d_in[0];
    const float* rw = (const float*)d_in[1];
    const float* qa = (const float*)d_in[2];
    const float* qb = (const float*)d_in[3];
    const float* va = (const float*)d_in[4];
    const float* vb = (const float*)d_in[5];
    float* out = (float*)d_out;

    const int T = in_sizes[0] / TOK_I;   // 16384 tokens (element counts)
    float* qout = out;
    float* vout = out + (long)T * NQ;

    // workspace layout
    size_t off_count = 0;                                  // 8 ints (256B slot)
    size_t off_gate  = 256;                                // T floats
    size_t off_tlist = off_gate + (size_t)T * 4;           // NE*T ints
    size_t off_low   = off_tlist + (size_t)NE * T * 4;     // T*32 floats
    size_t req       = off_low + (size_t)T * 32 * 4;

    if (ws_size < req || d_ws == nullptr) {
        // not enough workspace: previous verified single-kernel path
        qvlora_fused_kernel<<<T, 256, 0, stream>>>(h, rw, qa, qb, va, vb, qout, vout);
        return;
    }

    char*  ws    = (char*)d_ws;
    int*   count = (int*)(ws + off_count);
    float* gate  = (float*)(ws + off_gate);
    int*   tlist = (int*)(ws + off_tlist);
    float* low   = (float*)(ws + off_low);

    hipMemsetAsync(count, 0, 256, stream);
    router_kernel<<<(T + 1) / 2, 256, 0, stream>>>(h, rw, gate, tlist, count, T);
    dim3 g2((T + BM2 - 1) / BM2, NE);
    lowrank_kernel<<<g2, 256, 0, stream>>>(h, qa, va, gate, tlist, count, low, T);
    dim3 g3((T + BM3 - 1) / BM3, NE);
    expand_kernel<<<g3, 256, 0, stream>>>(low, qb, vb, tlist, count, qout, vout, T);
}